// Round 7
// baseline (1644.221 us; speedup 1.0000x reference)
//
#include <hip/hip_runtime.h>
#include <hip/hip_cooperative_groups.h>
#include <math.h>

namespace cg = cooperative_groups;
typedef float4 f4;

#define NT 1024         // 16 waves/block, 1 block/CU -> 4 waves/SIMD
#define RB 32           // rows per block; GRID=256 (proven cooperative size)

// ---------------- workspace float offsets (R1/R6 map) ----------------
#define WS_R     0          // R[128][128]
#define WS_W2T   16384      // W2T[128][128]  W2T[k][a] = W2[a][k]
#define WS_PART  32768      // [10][256]
#define WS_YZ    35328      // y_z [8192][32]
#define WS_Y1Z   297472
#define WS_YL    559616
#define WS_Y1L   567808
#define WS_KZ    576000     // k_z [7][8192][32]
#define WS_KL    2411008    // k_l [7][8192]
#define WS_TOTAL 2468352

// ---------------- LDS float offsets (63.6 KB, all f4-aligned pitches) ----
#define L_W1T   0           // [32][128]  W1T[j][h] = W1[h][j]
#define L_C3    4096        // [128][32]
#define L_P     8192        // [32][32]
#define L_HST   9216        // [128][36]  h transposed (init alias: IPW3)
#define L_XST   13824       // [32][36]   x transposed (init alias: IP; loop alias: RED[1024])
#define L_B1    14976
#define L_B2    15104
#define L_C0    15232
#define L_GS    15264       // [8][32]
#define L_AAUG  15520       // [8][16]
#define L_AINVG 15648       // [8][32]
#define L_MISC  15904       // [0]=trP
#define LDS_FLOATS 15905
#define L_RED   L_XST       // [1024] — XST(1152) is dead during the error reductions

__device__ const float ACO[5][5] = {
  { 0.2f, 0.f, 0.f, 0.f, 0.f },
  { (float)(3.0/40.0), (float)(9.0/40.0), 0.f, 0.f, 0.f },
  { (float)(44.0/45.0), (float)(-56.0/15.0), (float)(32.0/9.0), 0.f, 0.f },
  { (float)(19372.0/6561.0), (float)(-25360.0/2187.0), (float)(64448.0/6561.0), (float)(-212.0/729.0), 0.f },
  { (float)(9017.0/3168.0), (float)(-355.0/33.0), (float)(46732.0/5247.0), (float)(49.0/176.0), (float)(-5103.0/18656.0) }
};

#define B1C ((float)(35.0/384.0))
#define B3C ((float)(500.0/1113.0))
#define B4C ((float)(125.0/192.0))
#define B5C ((float)(-2187.0/6784.0))
#define B6C ((float)(11.0/84.0))

#define E1C ((float)(35.0/384.0 - 5179.0/57600.0))
#define E3C ((float)(500.0/1113.0 - 7571.0/16695.0))
#define E4C ((float)(125.0/192.0 - 393.0/640.0))
#define E5C ((float)(-2187.0/6784.0 + 92097.0/339200.0))
#define E6C ((float)(11.0/84.0 - 187.0/2100.0))
#define E7C ((float)(-1.0/40.0))

__device__ __forceinline__ f4 ld4(const float* p){ return *(const f4*)p; }
__device__ __forceinline__ void st4(float* p, f4 v){ *(f4*)p = v; }

// assemble x = y + dtc*sum_p co[p]*k[p] into xsT (transposed, pitch 36)
__device__ void assemble_x(float* lds, const float* __restrict__ ws, int r0, int tid,
                           float dtc, const float* co, int np)
{
  __syncthreads();
  if (tid < 256){
    const int r = tid >> 3, jj = (tid & 7) * 4;     // r 0..31, jj 0..28
    const int base = (r0 + r) * 32 + jj;
    f4 y = ld4(&ws[WS_YZ + base]);
    float sx = 0.f, sy = 0.f, sz = 0.f, sw = 0.f;
    for (int p = 0; p < np; p++){
      f4 kv = ld4(&ws[WS_KZ + p * 262144 + base]);
      float c = co[p];
      sx += c * kv.x; sy += c * kv.y; sz += c * kv.z; sw += c * kv.w;
    }
    lds[L_XST + (jj + 0) * 36 + r] = y.x + dtc * sx;
    lds[L_XST + (jj + 1) * 36 + r] = y.y + dtc * sy;
    lds[L_XST + (jj + 2) * 36 + r] = y.z + dtc * sz;
    lds[L_XST + (jj + 3) * 36 + r] = y.w + dtc * sw;
  }
  __syncthreads();
}

// full f-eval: xsT -> k_z[kout], k_l[kout]
// thread = (cg = tid&31: 4 cols, kh = (tid>>5)&1: k-half, wv = (tid>>6)&7: 4 rows,
//           grp = tid>>9: 0 = {phase1, ah, h2, phase3}, 1 = {at, dlogp})
__device__ void eval_f(float* lds, float* __restrict__ ws, int r0, int tid,
                       float trP, int kout)
{
  const int cg = tid & 31, kh = (tid >> 5) & 1, wv = (tid >> 6) & 7, grp = tid >> 9;
  const int row4 = 4 * wv;

  // ---- phase 1 (grp 0 only): h1 = relu(x @ W1^T + b1) -> hsT ----
  if (grp == 0){
    float a1[4][4];
#pragma unroll
    for (int i = 0; i < 4; i++)
#pragma unroll
      for (int j = 0; j < 4; j++) a1[i][j] = 0.f;
#pragma unroll 4
    for (int t = 0; t < 16; t++){
      const int k = kh * 16 + t;
      f4 av = ld4(&lds[L_XST + k * 36 + row4]);
      f4 bv = ld4(&lds[L_W1T + k * 128 + 4 * cg]);
      const float* ap = (const float*)&av;
      const float* bp = (const float*)&bv;
#pragma unroll
      for (int i = 0; i < 4; i++)
#pragma unroll
        for (int j = 0; j < 4; j++) a1[i][j] += bp[i] * ap[j];
    }
#pragma unroll
    for (int i = 0; i < 4; i++)
#pragma unroll
      for (int j = 0; j < 4; j++) a1[i][j] += __shfl_xor(a1[i][j], 32);
    if (kh == 0){
      f4 b1v = ld4(&lds[L_B1 + 4 * cg]);
      const float* b1p = (const float*)&b1v;
#pragma unroll
      for (int i = 0; i < 4; i++){
        f4 hv; float* hp = (float*)&hv;
#pragma unroll
        for (int j = 0; j < 4; j++) hp[j] = fmaxf(a1[i][j] + b1p[i], 0.f);
        st4(&lds[L_HST + (4 * cg + i) * 36 + row4], hv);
      }
    }
  }
  __syncthreads();

  // ---- phase 2 accumulate: grp0 -> ah (W2T), grp1 -> at (R) ----
  const int kb = kh * 64;
  float ac[4][4];
#pragma unroll
  for (int i = 0; i < 4; i++)
#pragma unroll
    for (int j = 0; j < 4; j++) ac[i][j] = 0.f;

  const f4* M4 = (const f4*)&ws[(grp == 0) ? WS_W2T : WS_R];
  f4 mb[4];
#pragma unroll
  for (int u = 0; u < 4; u++) mb[u] = M4[(kb + u) * 32 + cg];

  if (grp == 0){
#pragma unroll 1
    for (int g = 0; g < 16; g++){
      f4 mc[4];
#pragma unroll
      for (int u = 0; u < 4; u++) mc[u] = mb[u];
      if (g < 15){
        const int kn = kb + (g + 1) * 4;
#pragma unroll
        for (int u = 0; u < 4; u++) mb[u] = M4[(kn + u) * 32 + cg];
      }
#pragma unroll
      for (int u = 0; u < 4; u++){
        const int k = kb + g * 4 + u;
        f4 av = ld4(&lds[L_HST + k * 36 + row4]);
        const float* ap = (const float*)&av;
        const float* wp = (const float*)&mc[u];
#pragma unroll
        for (int i = 0; i < 4; i++)
#pragma unroll
          for (int j = 0; j < 4; j++) ac[i][j] += wp[i] * ap[j];
      }
    }
  } else {
#pragma unroll 1
    for (int g = 0; g < 16; g++){
      f4 mc[4];
#pragma unroll
      for (int u = 0; u < 4; u++) mc[u] = mb[u];
      if (g < 15){
        const int kn = kb + (g + 1) * 4;
#pragma unroll
        for (int u = 0; u < 4; u++) mb[u] = M4[(kn + u) * 32 + cg];
      }
#pragma unroll
      for (int u = 0; u < 4; u++){
        const int k = kb + g * 4 + u;
        f4 av = ld4(&lds[L_HST + k * 36 + row4]);
        const float* ap = (const float*)&av;
        const float* rp = (const float*)&mc[u];
        float m[4];
#pragma unroll
        for (int j = 0; j < 4; j++) m[j] = (ap[j] > 0.f) ? 1.f : 0.f;
#pragma unroll
        for (int i = 0; i < 4; i++)
#pragma unroll
          for (int j = 0; j < 4; j++) ac[i][j] += rp[i] * m[j];
      }
    }
  }
#pragma unroll
  for (int i = 0; i < 4; i++)
#pragma unroll
    for (int j = 0; j < 4; j++) ac[i][j] += __shfl_xor(ac[i][j], 32);

  // grp0: h2 = relu(ah + b2) in regs
  float h2v[4][4];
  if (grp == 0){
    f4 b2v = ld4(&lds[L_B2 + 4 * cg]);
    const float* b2p = (const float*)&b2v;
#pragma unroll
    for (int i = 0; i < 4; i++)
#pragma unroll
      for (int j = 0; j < 4; j++) h2v[i][j] = fmaxf(ac[i][j] + b2p[i], 0.f);
  }
  __syncthreads();                 // barrier A: all h1 readers done
  if (grp == 0 && kh == 0){
#pragma unroll
    for (int i = 0; i < 4; i++){
      f4 hv; float* hp = (float*)&hv;
#pragma unroll
      for (int j = 0; j < 4; j++) hp[j] = h2v[i][j];
      st4(&lds[L_HST + (4 * cg + i) * 36 + row4], hv);
    }
  }
  __syncthreads();                 // barrier B: h2 visible

  if (grp == 1){
    // ---- dlogp: gate at by m2 = (h2 > 0), reduce across cols ----
    float dl[4] = {0.f, 0.f, 0.f, 0.f};
#pragma unroll
    for (int i = 0; i < 4; i++){
      f4 hv = ld4(&lds[L_HST + (4 * cg + i) * 36 + row4]);
      const float* hp = (const float*)&hv;
#pragma unroll
      for (int j = 0; j < 4; j++)
        if (hp[j] > 0.f) dl[j] += ac[i][j];
    }
#pragma unroll
    for (int mk = 1; mk < 32; mk <<= 1){
#pragma unroll
      for (int j = 0; j < 4; j++) dl[j] += __shfl_xor(dl[j], mk, 64);
    }
    if (kh == 0 && cg == 0){
#pragma unroll
      for (int j = 0; j < 4; j++)
        ws[WS_KL + kout * 8192 + r0 + row4 + j] = dl[j] + trP;
    }
  } else {
    // ---- phase 3: dz = -(h2 @ C3 + c0 + x @ P); b,q split over halves ----
    float a3[4] = {0.f, 0.f, 0.f, 0.f};
#pragma unroll 8
    for (int t = 0; t < 64; t++){
      const int b = kh * 64 + t;
      f4 av = ld4(&lds[L_HST + b * 36 + row4]);
      const float* ap = (const float*)&av;
      float w3 = lds[L_C3 + b * 32 + cg];
#pragma unroll
      for (int j = 0; j < 4; j++) a3[j] += ap[j] * w3;
    }
#pragma unroll 8
    for (int t = 0; t < 16; t++){
      const int q = kh * 16 + t;
      f4 av = ld4(&lds[L_XST + q * 36 + row4]);
      const float* ap = (const float*)&av;
      float pv = lds[L_P + q * 32 + cg];
#pragma unroll
      for (int j = 0; j < 4; j++) a3[j] += ap[j] * pv;
    }
#pragma unroll
    for (int j = 0; j < 4; j++) a3[j] += __shfl_xor(a3[j], 32);
    if (kh == 0){
      float c0v = lds[L_C0 + cg];
#pragma unroll
      for (int j = 0; j < 4; j++)
        ws[WS_KZ + kout * 262144 + (r0 + row4 + j) * 32 + cg] = -(a3[j] + c0v);
    }
  }
}

__global__ void __launch_bounds__(NT, 4)
qpnf_kernel(const float* __restrict__ z, const float* __restrict__ Gw,
            const float* __restrict__ W1g, const float* __restrict__ b1g,
            const float* __restrict__ W2g, const float* __restrict__ b2g,
            const float* __restrict__ W3g, const float* __restrict__ b3g,
            const float* __restrict__ Tg, float* __restrict__ out,
            float* __restrict__ ws)
{
  __shared__ float lds[LDS_FLOATS];
  const int tid = threadIdx.x;
  const int bid = blockIdx.x;
  const int r0 = bid * RB;
  cg::grid_group grid = cg::this_grid();

  // ================= init =================
  for (int i = 0; i < 4; i++){                // W1T[j][h] = W1[h][j]
    int idx = tid + i * NT;
    int h = idx >> 5, j = idx & 31;
    lds[L_W1T + j * 128 + h] = W1g[idx];
  }
  if (tid < 128){ lds[L_B1 + tid] = b1g[tid]; lds[L_B2 + tid] = b2g[tid]; }
  if (tid < 256) lds[L_GS + tid] = Gw[tid];
  __syncthreads();

  if (tid < 64){                              // A = G G^T (8x8), augmented
    int i = tid >> 3, j = tid & 7;
    float s = 0.f;
    for (int k = 0; k < 32; k++) s += lds[L_GS + i * 32 + k] * lds[L_GS + j * 32 + k];
    lds[L_AAUG + i * 16 + j] = s;
    lds[L_AAUG + i * 16 + 8 + j] = (i == j) ? 1.f : 0.f;
  }
  __syncthreads();
  if (tid == 0){                              // Gauss-Jordan, partial pivoting
    float* A = &lds[L_AAUG];
    for (int c = 0; c < 8; c++){
      int p = c; float mx = fabsf(A[c * 16 + c]);
      for (int r = c + 1; r < 8; r++){
        float v = fabsf(A[r * 16 + c]);
        if (v > mx){ mx = v; p = r; }
      }
      if (p != c)
        for (int q = 0; q < 16; q++){ float t = A[c*16+q]; A[c*16+q] = A[p*16+q]; A[p*16+q] = t; }
      float pv = 1.0f / A[c * 16 + c];
      for (int q = 0; q < 16; q++) A[c * 16 + q] *= pv;
      for (int r = 0; r < 8; r++) if (r != c){
        float fct = A[r * 16 + c];
        for (int q = 0; q < 16; q++) A[r * 16 + q] -= fct * A[c * 16 + q];
      }
    }
  }
  __syncthreads();
  if (tid < 256){                              // AinvG[m][d]
    int m = tid >> 5, d = tid & 31;
    float s = 0.f;
    for (int q = 0; q < 8; q++) s += lds[L_AAUG + m * 16 + 8 + q] * lds[L_GS + q * 32 + d];
    lds[L_AINVG + m * 32 + d] = s;
  }
  __syncthreads();
  {                                            // P = G^T AinvG (1024 elems = NT)
    int i = tid >> 5, j = tid & 31;
    float s = 0.f;
    for (int m = 0; m < 8; m++) s += lds[L_GS + m * 32 + i] * lds[L_AINVG + m * 32 + j];
    lds[L_P + i * 32 + j] = s;
  }
  __syncthreads();
  float* IPl = &lds[L_XST];                    // IP aliases XST during init
  {
    int i = tid >> 5, j = tid & 31;
    IPl[i * 32 + j] = ((i == j) ? 1.f : 0.f) - lds[L_P + i * 32 + j];
  }
  if (tid == 0){
    float s = 0.f;
    for (int i = 0; i < 32; i++) s += lds[L_P + i * 32 + i];
    lds[L_MISC] = s;                           // trP
  }
  __syncthreads();
  for (int i4 = 0; i4 < 4; i4++){              // C3[b][c] = sum_i W3[i][b] IP[i][c]
    int idx = tid + i4 * NT;
    int b = idx >> 5, c = idx & 31;
    float s = 0.f;
    for (int i = 0; i < 32; i++) s += W3g[i * 128 + b] * IPl[i * 32 + c];
    lds[L_C3 + b * 32 + c] = s;
  }
  if (tid < 32){                               // c0 = b3 @ IP
    float s = 0.f;
    for (int i = 0; i < 32; i++) s += b3g[i] * IPl[i * 32 + tid];
    lds[L_C0 + tid] = s;
  }
  for (int i4 = 0; i4 < 4; i4++){              // IPW3[j][b] (aliases HST)
    int idx = tid + i4 * NT;
    int j = idx >> 7, b = idx & 127;
    float s = 0.f;
    for (int k = 0; k < 32; k++) s += IPl[j * 32 + k] * W3g[k * 128 + b];
    lds[L_HST + j * 128 + b] = s;
  }
  __syncthreads();
  if (bid < 128 && tid < 128){                 // R row a=bid
    int a = bid;
    float s = 0.f;
    for (int j = 0; j < 32; j++) s += W1g[a * 32 + j] * lds[L_HST + j * 128 + tid];
    ws[WS_R + a * 128 + tid] = s * W2g[tid * 128 + a];
  }
  if (bid >= 128 && tid < 128){                // W2T row a
    int a = bid - 128;
    ws[WS_W2T + a * 128 + tid] = W2g[tid * 128 + a];
  }
  if (tid < 256){                              // y0 = [z, 0]
    const int r = tid >> 3, jj = (tid & 7) * 4;
    const int base = (r0 + r) * 32 + jj;
    st4(&ws[WS_YZ + base], ld4(&z[base]));
  }
  if (tid < RB) ws[WS_YL + r0 + tid] = 0.f;

  const float trP = lds[L_MISC];
  const float t1 = 2.0f * Tg[0];

  grid.sync();

  // ================= main adaptive RK loop =================
  float t_cur = 0.f, dt_cur = 0.25f;
  bool prev_acc = false;

  for (int step = 0; step < 10; step++){
    if (t_cur >= t1 - 1e-9f) break;            // remaining reference steps no-op
    const float dtc = fminf(dt_cur, t1 - t_cur);

    // stages 1..6
    for (int s = 1; s <= 6; s++){
      if (s == 1 && step > 0){
        if (prev_acc){                         // FSAL: k1 = previous k7
          if (tid < 256){
            const int r = tid >> 3, jj = (tid & 7) * 4;
            const int base = (r0 + r) * 32 + jj;
            st4(&ws[WS_KZ + 0 * 262144 + base], ld4(&ws[WS_KZ + 6 * 262144 + base]));
          }
          if (tid < RB) ws[WS_KL + 0 * 8192 + r0 + tid] = ws[WS_KL + 6 * 8192 + r0 + tid];
        }                                       // rejected: k1 = f(y) unchanged
        continue;
      }
      assemble_x(lds, ws, r0, tid, dtc, ACO[s >= 2 ? s - 2 : 0], s - 1);
      eval_f(lds, ws, r0, tid, trP, s - 1);
    }

    // stage 7: y1, k7 = f(y1), error estimate
    __syncthreads();
    if (tid < 256){
      const int r = tid >> 3, jj = (tid & 7) * 4;
      const int base = (r0 + r) * 32 + jj;
      f4 y   = ld4(&ws[WS_YZ + base]);
      f4 k1v = ld4(&ws[WS_KZ + 0 * 262144 + base]);
      f4 k3v = ld4(&ws[WS_KZ + 2 * 262144 + base]);
      f4 k4v = ld4(&ws[WS_KZ + 3 * 262144 + base]);
      f4 k5v = ld4(&ws[WS_KZ + 4 * 262144 + base]);
      f4 k6v = ld4(&ws[WS_KZ + 5 * 262144 + base]);
      f4 x;
      x.x = y.x + dtc * (B1C*k1v.x + B3C*k3v.x + B4C*k4v.x + B5C*k5v.x + B6C*k6v.x);
      x.y = y.y + dtc * (B1C*k1v.y + B3C*k3v.y + B4C*k4v.y + B5C*k5v.y + B6C*k6v.y);
      x.z = y.z + dtc * (B1C*k1v.z + B3C*k3v.z + B4C*k4v.z + B5C*k5v.z + B6C*k6v.z);
      x.w = y.w + dtc * (B1C*k1v.w + B3C*k3v.w + B4C*k4v.w + B5C*k5v.w + B6C*k6v.w);
      st4(&ws[WS_Y1Z + base], x);
      lds[L_XST + (jj + 0) * 36 + r] = x.x;
      lds[L_XST + (jj + 1) * 36 + r] = x.y;
      lds[L_XST + (jj + 2) * 36 + r] = x.z;
      lds[L_XST + (jj + 3) * 36 + r] = x.w;
    }
    if (tid < RB){
      int n = r0 + tid;
      float s = B1C * ws[WS_KL + 0*8192 + n] + B3C * ws[WS_KL + 2*8192 + n]
              + B4C * ws[WS_KL + 3*8192 + n] + B5C * ws[WS_KL + 4*8192 + n]
              + B6C * ws[WS_KL + 5*8192 + n];
      ws[WS_Y1L + n] = ws[WS_YL + n] + dtc * s;
    }
    __syncthreads();
    eval_f(lds, ws, r0, tid, trP, 6);
    __syncthreads();

    float sacc = 0.f;
    if (tid < 256){
      const int r = tid >> 3, jj = (tid & 7) * 4;
      const int base = (r0 + r) * 32 + jj;
      f4 k1v = ld4(&ws[WS_KZ + 0 * 262144 + base]);
      f4 k3v = ld4(&ws[WS_KZ + 2 * 262144 + base]);
      f4 k4v = ld4(&ws[WS_KZ + 3 * 262144 + base]);
      f4 k5v = ld4(&ws[WS_KZ + 4 * 262144 + base]);
      f4 k6v = ld4(&ws[WS_KZ + 5 * 262144 + base]);
      f4 k7v = ld4(&ws[WS_KZ + 6 * 262144 + base]);
      f4 yv  = ld4(&ws[WS_YZ + base]);
      f4 y1v = ld4(&ws[WS_Y1Z + base]);
      float ev, tol, q;
      ev = dtc * (E1C*k1v.x + E3C*k3v.x + E4C*k4v.x + E5C*k5v.x + E6C*k6v.x + E7C*k7v.x);
      tol = 1e-5f + 1e-5f * fmaxf(fabsf(yv.x), fabsf(y1v.x)); q = ev / tol; sacc += q * q;
      ev = dtc * (E1C*k1v.y + E3C*k3v.y + E4C*k4v.y + E5C*k5v.y + E6C*k6v.y + E7C*k7v.y);
      tol = 1e-5f + 1e-5f * fmaxf(fabsf(yv.y), fabsf(y1v.y)); q = ev / tol; sacc += q * q;
      ev = dtc * (E1C*k1v.z + E3C*k3v.z + E4C*k4v.z + E5C*k5v.z + E6C*k6v.z + E7C*k7v.z);
      tol = 1e-5f + 1e-5f * fmaxf(fabsf(yv.z), fabsf(y1v.z)); q = ev / tol; sacc += q * q;
      ev = dtc * (E1C*k1v.w + E3C*k3v.w + E4C*k4v.w + E5C*k5v.w + E6C*k6v.w + E7C*k7v.w);
      tol = 1e-5f + 1e-5f * fmaxf(fabsf(yv.w), fabsf(y1v.w)); q = ev / tol; sacc += q * q;
    }
    if (tid < RB){
      int n = r0 + tid;
      float evl = dtc * (E1C * ws[WS_KL + 0*8192 + n] + E3C * ws[WS_KL + 2*8192 + n]
                + E4C * ws[WS_KL + 3*8192 + n] + E5C * ws[WS_KL + 4*8192 + n]
                + E6C * ws[WS_KL + 5*8192 + n] + E7C * ws[WS_KL + 6*8192 + n]);
      float toll = 1e-5f + 1e-5f * fmaxf(fabsf(ws[WS_YL + n]), fabsf(ws[WS_Y1L + n]));
      float ql = evl / toll; sacc += ql * ql;
    }
    lds[L_RED + tid] = sacc; __syncthreads();
    for (int o = 512; o > 0; o >>= 1){
      if (tid < o) lds[L_RED + tid] += lds[L_RED + tid + o];
      __syncthreads();
    }
    if (tid == 0) ws[WS_PART + step * 256 + bid] = lds[L_RED + 0];

    grid.sync();

    // deterministic global reduction (every block, identical order)
    if (tid < 256) lds[L_RED + tid] = ws[WS_PART + step * 256 + tid];
    __syncthreads();
    for (int o = 128; o > 0; o >>= 1){
      if (tid < o) lds[L_RED + tid] += lds[L_RED + tid + o];
      __syncthreads();
    }
    const float errn = sqrtf(lds[L_RED + 0] / 270336.0f);
    __syncthreads();

    const bool accept = (errn <= 1.0f);
    if (accept){
      if (tid < 256){
        const int r = tid >> 3, jj = (tid & 7) * 4;
        const int base = (r0 + r) * 32 + jj;
        st4(&ws[WS_YZ + base], ld4(&ws[WS_Y1Z + base]));
      }
      if (tid < RB) ws[WS_YL + r0 + tid] = ws[WS_Y1L + r0 + tid];
      t_cur += dtc;
    }
    float fac = 0.9f * powf(errn, -0.2f);
    fac = fminf(fmaxf(fac, 0.2f), 10.0f);
    dt_cur = fminf(fmaxf(dtc * fac, 1e-6f), t1);
    prev_acc = accept;
  }

  // ---- output: yT[:, :d] ----
  if (tid < 256){
    const int r = tid >> 3, jj = (tid & 7) * 4;
    const int base = (r0 + r) * 32 + jj;
    st4(&out[base], ld4(&ws[WS_YZ + base]));
  }
}

extern "C" void kernel_launch(void* const* d_in, const int* in_sizes, int n_in,
                              void* d_out, int out_size, void* d_ws, size_t ws_size,
                              hipStream_t stream)
{
  (void)in_sizes; (void)n_in; (void)out_size;
  const float* z  = (const float*)d_in[0];
  const float* Gw = (const float*)d_in[1];
  const float* W1 = (const float*)d_in[2];
  const float* b1 = (const float*)d_in[3];
  const float* W2 = (const float*)d_in[4];
  const float* b2 = (const float*)d_in[5];
  const float* W3 = (const float*)d_in[6];
  const float* b3 = (const float*)d_in[7];
  const float* T  = (const float*)d_in[8];
  float* out = (float*)d_out;
  float* ws  = (float*)d_ws;
  if (ws_size < (size_t)WS_TOTAL * sizeof(float)) return;

  void* args[] = { (void*)&z, (void*)&Gw, (void*)&W1, (void*)&b1, (void*)&W2,
                   (void*)&b2, (void*)&W3, (void*)&b3, (void*)&T, (void*)&out,
                   (void*)&ws };
  hipLaunchCooperativeKernel((const void*)qpnf_kernel, dim3(256), dim3(NT),
                             args, 0, stream);
}

// Round 8
// 1360.092 us; speedup vs baseline: 1.2089x; 1.2089x over previous
//
#include <hip/hip_runtime.h>
#include <hip/hip_cooperative_groups.h>
#include <math.h>

namespace cg = cooperative_groups;
typedef float4 f4;

#define NT 512          // 8 waves/block, 1 block/CU -> 2 waves/SIMD
#define RB 32           // rows per block; GRID=256 (cooperative cap)

// ---------------- workspace float offsets ----------------
#define WS_WR    0          // WR[128][256]: [k][0:128]=W2T row k (=W2[:,k]), [k][128:256]=R row k
#define WS_PART  32768      // [10][256]
#define WS_YZ    35328      // y_z [8192][32]
#define WS_Y1Z   297472
#define WS_YL    559616
#define WS_Y1L   567808
#define WS_KZ    576000     // k_z [7][8192][32]
#define WS_KL    2411008    // k_l [7][8192]
#define WS_TOTAL 2468352

// ---------------- LDS float offsets (~87 KB, f4-aligned pitches) ----------
#define L_W1T   0           // [32][128]  W1T[j][h] = W1[h][j]
#define L_C3T   4096        // [32][132]  C3T[c][b] = C3[b][c], pitch 132
#define L_P     8320        // [32][32]   (init only)
#define L_PT    9344        // [32][36]   PT[c][q] = P[q][c]
#define L_HST   10496       // [128][36]  h1 transposed (init alias: IPW3)
#define L_HS2   15104       // [128][36]  h2 transposed
#define L_XST   19712       // [32][36]   x transposed (init alias: IP; loop alias: RED[512])
#define L_B1    20864
#define L_B2    20992
#define L_C0    21120
#define L_GS    21152       // [8][32]
#define L_AAUG  21408       // [8][16]
#define L_AINVG 21536       // [8][32]
#define L_MISC  21792       // [0]=trP
#define LDS_FLOATS 21793
#define L_RED   L_XST       // [512] — XST is dead during the error reductions

__device__ const float ACO[5][5] = {
  { 0.2f, 0.f, 0.f, 0.f, 0.f },
  { (float)(3.0/40.0), (float)(9.0/40.0), 0.f, 0.f, 0.f },
  { (float)(44.0/45.0), (float)(-56.0/15.0), (float)(32.0/9.0), 0.f, 0.f },
  { (float)(19372.0/6561.0), (float)(-25360.0/2187.0), (float)(64448.0/6561.0), (float)(-212.0/729.0), 0.f },
  { (float)(9017.0/3168.0), (float)(-355.0/33.0), (float)(46732.0/5247.0), (float)(49.0/176.0), (float)(-5103.0/18656.0) }
};

#define B1C ((float)(35.0/384.0))
#define B3C ((float)(500.0/1113.0))
#define B4C ((float)(125.0/192.0))
#define B5C ((float)(-2187.0/6784.0))
#define B6C ((float)(11.0/84.0))

#define E1C ((float)(35.0/384.0 - 5179.0/57600.0))
#define E3C ((float)(500.0/1113.0 - 7571.0/16695.0))
#define E4C ((float)(125.0/192.0 - 393.0/640.0))
#define E5C ((float)(-2187.0/6784.0 + 92097.0/339200.0))
#define E6C ((float)(11.0/84.0 - 187.0/2100.0))
#define E7C ((float)(-1.0/40.0))

__device__ __forceinline__ f4 ld4(const float* p){ return *(const f4*)p; }
__device__ __forceinline__ void st4(float* p, f4 v){ *(f4*)p = v; }

// assemble x = y + dtc*sum_p co[p]*k[p] into xsT (transposed, pitch 36)
__device__ void assemble_x(float* lds, const float* __restrict__ ws, int r0, int tid,
                           float dtc, const float* co, int np)
{
  __syncthreads();
  if (tid < 256){
    const int r = tid >> 3, jj = (tid & 7) * 4;     // r 0..31, jj 0..28
    const int base = (r0 + r) * 32 + jj;
    f4 y = ld4(&ws[WS_YZ + base]);
    float sx = 0.f, sy = 0.f, sz = 0.f, sw = 0.f;
    for (int p = 0; p < np; p++){
      f4 kv = ld4(&ws[WS_KZ + p * 262144 + base]);
      float c = co[p];
      sx += c * kv.x; sy += c * kv.y; sz += c * kv.z; sw += c * kv.w;
    }
    lds[L_XST + (jj + 0) * 36 + r] = y.x + dtc * sx;
    lds[L_XST + (jj + 1) * 36 + r] = y.y + dtc * sy;
    lds[L_XST + (jj + 2) * 36 + r] = y.z + dtc * sz;
    lds[L_XST + (jj + 3) * 36 + r] = y.w + dtc * sw;
  }
  __syncthreads();
}

// full f-eval: xsT -> k_z[kout], k_l[kout]
// thread = (cg = tid&31: 4 cols, kh = (tid>>5)&1: k-half, wv = tid>>6: 4 rows)
__device__ void eval_f(float* lds, float* __restrict__ ws, int r0, int tid,
                       float trP, int kout)
{
  const int cg = tid & 31, kh = (tid >> 5) & 1, wv = tid >> 6;
  const int row4 = 4 * wv;

  // ---- phase 1: h1 = relu(x @ W1^T + b1) -> HST ; k split over halves ----
  float a1[4][4];
#pragma unroll
  for (int i = 0; i < 4; i++)
#pragma unroll
    for (int j = 0; j < 4; j++) a1[i][j] = 0.f;
#pragma unroll 4
  for (int t = 0; t < 16; t++){
    const int k = kh * 16 + t;
    f4 av = ld4(&lds[L_XST + k * 36 + row4]);
    f4 bv = ld4(&lds[L_W1T + k * 128 + 4 * cg]);
    const float* ap = (const float*)&av;
    const float* bp = (const float*)&bv;
#pragma unroll
    for (int i = 0; i < 4; i++)
#pragma unroll
      for (int j = 0; j < 4; j++) a1[i][j] += bp[i] * ap[j];
  }
#pragma unroll
  for (int i = 0; i < 4; i++)
#pragma unroll
    for (int j = 0; j < 4; j++) a1[i][j] += __shfl_xor(a1[i][j], 32);
  if (kh == 0){
    f4 b1v = ld4(&lds[L_B1 + 4 * cg]);
    const float* b1p = (const float*)&b1v;
#pragma unroll
    for (int i = 0; i < 4; i++){
      f4 hv; float* hp = (float*)&hv;
#pragma unroll
      for (int j = 0; j < 4; j++) hp[j] = fmaxf(a1[i][j] + b1p[i], 0.f);
      st4(&lds[L_HST + (4 * cg + i) * 36 + row4], hv);
    }
  }
  __syncthreads();

  // ---- phase 2: ah = h1@W2^T, at = m1^T R ; WR interleaved stream ----
  float ah[4][4], at[4][4];
#pragma unroll
  for (int i = 0; i < 4; i++)
#pragma unroll
    for (int j = 0; j < 4; j++){ ah[i][j] = 0.f; at[i][j] = 0.f; }
  const f4* WR4 = (const f4*)&ws[WS_WR];   // row k = 64 f4: [0:32)=W2T, [32:64)=R
  const int kb = kh * 64;
  f4 wb[4], rb[4];
#pragma unroll
  for (int u = 0; u < 4; u++){
    wb[u] = WR4[(kb + u) * 64 + cg];
    rb[u] = WR4[(kb + u) * 64 + 32 + cg];
  }
#pragma unroll 1
  for (int g = 0; g < 16; g++){
    f4 wc[4], rc[4];
#pragma unroll
    for (int u = 0; u < 4; u++){ wc[u] = wb[u]; rc[u] = rb[u]; }
    if (g < 15){
      const int kn = kb + (g + 1) * 4;
#pragma unroll
      for (int u = 0; u < 4; u++){
        wb[u] = WR4[(kn + u) * 64 + cg];
        rb[u] = WR4[(kn + u) * 64 + 32 + cg];
      }
    }
#pragma unroll
    for (int u = 0; u < 4; u++){
      const int k = kb + g * 4 + u;
      f4 av = ld4(&lds[L_HST + k * 36 + row4]);
      const float* ap = (const float*)&av;
      const float* wp = (const float*)&wc[u];
      const float* rp = (const float*)&rc[u];
      float m[4];
#pragma unroll
      for (int j = 0; j < 4; j++) m[j] = (ap[j] > 0.f) ? 1.f : 0.f;
#pragma unroll
      for (int i = 0; i < 4; i++)
#pragma unroll
        for (int j = 0; j < 4; j++){
          ah[i][j] += wp[i] * ap[j];
          at[i][j] += rp[i] * m[j];
        }
    }
  }
#pragma unroll
  for (int i = 0; i < 4; i++)
#pragma unroll
    for (int j = 0; j < 4; j++){
      ah[i][j] += __shfl_xor(ah[i][j], 32);
      at[i][j] += __shfl_xor(at[i][j], 32);
    }

  f4 b2v = ld4(&lds[L_B2 + 4 * cg]);
  const float* b2p = (const float*)&b2v;
  float h2v[4][4]; float dl[4] = {0.f, 0.f, 0.f, 0.f};
#pragma unroll
  for (int i = 0; i < 4; i++)
#pragma unroll
    for (int j = 0; j < 4; j++){
      float pre = ah[i][j] + b2p[i];
      float hv = fmaxf(pre, 0.f);
      h2v[i][j] = hv;
      if (pre > 0.f) dl[j] += at[i][j];
    }
#pragma unroll
  for (int mk = 1; mk < 32; mk <<= 1){
#pragma unroll
    for (int j = 0; j < 4; j++) dl[j] += __shfl_xor(dl[j], mk, 64);
  }
  // h2 goes to HS2 (separate buffer) — no barrier needed before the store
  if (kh == 0){
#pragma unroll
    for (int i = 0; i < 4; i++){
      f4 hv; float* hp = (float*)&hv;
#pragma unroll
      for (int j = 0; j < 4; j++) hp[j] = h2v[i][j];
      st4(&lds[L_HS2 + (4 * cg + i) * 36 + row4], hv);
    }
    if (cg == 0){
#pragma unroll
      for (int j = 0; j < 4; j++)
        ws[WS_KL + kout * 8192 + r0 + row4 + j] = dl[j] + trP;
    }
  }
  __syncthreads();                 // h2 visible

  // ---- phase 3: dz = -(h2 @ C3 + c0 + x @ P); f4 weight reads ----
  float a3[4] = {0.f, 0.f, 0.f, 0.f};
  const int bb = kh * 64;
#pragma unroll 4
  for (int t = 0; t < 16; t++){
    f4 cv = ld4(&lds[L_C3T + cg * 132 + bb + 4 * t]);
    const float* cp = (const float*)&cv;
#pragma unroll
    for (int u = 0; u < 4; u++){
      f4 av = ld4(&lds[L_HS2 + (bb + 4 * t + u) * 36 + row4]);
      const float* ap = (const float*)&av;
#pragma unroll
      for (int j = 0; j < 4; j++) a3[j] += ap[j] * cp[u];
    }
  }
  const int qq = kh * 16;
#pragma unroll
  for (int t = 0; t < 4; t++){
    f4 pv = ld4(&lds[L_PT + cg * 36 + qq + 4 * t]);
    const float* pp = (const float*)&pv;
#pragma unroll
    for (int u = 0; u < 4; u++){
      f4 av = ld4(&lds[L_XST + (qq + 4 * t + u) * 36 + row4]);
      const float* ap = (const float*)&av;
#pragma unroll
      for (int j = 0; j < 4; j++) a3[j] += ap[j] * pp[u];
    }
  }
#pragma unroll
  for (int j = 0; j < 4; j++) a3[j] += __shfl_xor(a3[j], 32);
  if (kh == 0){
    float c0v = lds[L_C0 + cg];
#pragma unroll
    for (int j = 0; j < 4; j++)
      ws[WS_KZ + kout * 262144 + (r0 + row4 + j) * 32 + cg] = -(a3[j] + c0v);
  }
}

__global__ void __launch_bounds__(NT, 2)
qpnf_kernel(const float* __restrict__ z, const float* __restrict__ Gw,
            const float* __restrict__ W1g, const float* __restrict__ b1g,
            const float* __restrict__ W2g, const float* __restrict__ b2g,
            const float* __restrict__ W3g, const float* __restrict__ b3g,
            const float* __restrict__ Tg, float* __restrict__ out,
            float* __restrict__ ws)
{
  __shared__ float lds[LDS_FLOATS];
  const int tid = threadIdx.x;
  const int bid = blockIdx.x;
  const int r0 = bid * RB;
  cg::grid_group grid = cg::this_grid();

  // ================= init =================
  for (int i = 0; i < 8; i++){                // W1T[j][h] = W1[h][j]
    int idx = tid + i * NT;
    int h = idx >> 5, j = idx & 31;
    lds[L_W1T + j * 128 + h] = W1g[idx];
  }
  if (tid < 128){ lds[L_B1 + tid] = b1g[tid]; lds[L_B2 + tid] = b2g[tid]; }
  if (tid < 256) lds[L_GS + tid] = Gw[tid];
  __syncthreads();

  if (tid < 64){                              // A = G G^T (8x8), augmented
    int i = tid >> 3, j = tid & 7;
    float s = 0.f;
    for (int k = 0; k < 32; k++) s += lds[L_GS + i * 32 + k] * lds[L_GS + j * 32 + k];
    lds[L_AAUG + i * 16 + j] = s;
    lds[L_AAUG + i * 16 + 8 + j] = (i == j) ? 1.f : 0.f;
  }
  __syncthreads();
  if (tid == 0){                              // Gauss-Jordan, partial pivoting
    float* A = &lds[L_AAUG];
    for (int c = 0; c < 8; c++){
      int p = c; float mx = fabsf(A[c * 16 + c]);
      for (int r = c + 1; r < 8; r++){
        float v = fabsf(A[r * 16 + c]);
        if (v > mx){ mx = v; p = r; }
      }
      if (p != c)
        for (int q = 0; q < 16; q++){ float t = A[c*16+q]; A[c*16+q] = A[p*16+q]; A[p*16+q] = t; }
      float pv = 1.0f / A[c * 16 + c];
      for (int q = 0; q < 16; q++) A[c * 16 + q] *= pv;
      for (int r = 0; r < 8; r++) if (r != c){
        float fct = A[r * 16 + c];
        for (int q = 0; q < 16; q++) A[r * 16 + q] -= fct * A[c * 16 + q];
      }
    }
  }
  __syncthreads();
  if (tid < 256){                              // AinvG[m][d]
    int m = tid >> 5, d = tid & 31;
    float s = 0.f;
    for (int q = 0; q < 8; q++) s += lds[L_AAUG + m * 16 + 8 + q] * lds[L_GS + q * 32 + d];
    lds[L_AINVG + m * 32 + d] = s;
  }
  __syncthreads();
  for (int i4 = 0; i4 < 2; i4++){              // P = G^T AinvG
    int idx = tid + i4 * NT;
    int i = idx >> 5, j = idx & 31;
    float s = 0.f;
    for (int m = 0; m < 8; m++) s += lds[L_GS + m * 32 + i] * lds[L_AINVG + m * 32 + j];
    lds[L_P + i * 32 + j] = s;
  }
  __syncthreads();
  float* IPl = &lds[L_XST];                    // IP aliases XST during init
  for (int i4 = 0; i4 < 2; i4++){
    int idx = tid + i4 * NT;
    int i = idx >> 5, j = idx & 31;
    IPl[i * 32 + j] = ((i == j) ? 1.f : 0.f) - lds[L_P + i * 32 + j];
  }
  if (tid == 0){
    float s = 0.f;
    for (int i = 0; i < 32; i++) s += lds[L_P + i * 32 + i];
    lds[L_MISC] = s;                           // trP
  }
  __syncthreads();
  for (int i4 = 0; i4 < 8; i4++){              // C3T[c][b] = sum_i W3[i][b] IP[i][c]
    int idx = tid + i4 * NT;
    int b = idx & 127, c = idx >> 7;
    float s = 0.f;
    for (int i = 0; i < 32; i++) s += W3g[i * 128 + b] * IPl[i * 32 + c];
    lds[L_C3T + c * 132 + b] = s;
  }
  for (int i4 = 0; i4 < 2; i4++){              // PT[c][q] = P[q][c]
    int idx = tid + i4 * NT;
    int c = idx >> 5, q = idx & 31;
    lds[L_PT + c * 36 + q] = lds[L_P + q * 32 + c];
  }
  if (tid < 32){                               // c0 = b3 @ IP
    float s = 0.f;
    for (int i = 0; i < 32; i++) s += b3g[i] * IPl[i * 32 + tid];
    lds[L_C0 + tid] = s;
  }
  for (int i4 = 0; i4 < 8; i4++){              // IPW3[j][b] (aliases HST)
    int idx = tid + i4 * NT;
    int j = idx >> 7, b = idx & 127;
    float s = 0.f;
    for (int k = 0; k < 32; k++) s += IPl[j * 32 + k] * W3g[k * 128 + b];
    lds[L_HST + j * 128 + b] = s;
  }
  __syncthreads();
  if (bid < 128 && tid < 128){                 // R row a=bid -> WR[a][128+b]
    int a = bid;
    float s = 0.f;
    for (int j = 0; j < 32; j++) s += W1g[a * 32 + j] * lds[L_HST + j * 128 + tid];
    ws[WS_WR + a * 256 + 128 + tid] = s * W2g[tid * 128 + a];
  }
  if (bid >= 128 && tid < 128){                // W2T row a -> WR[a][b]
    int a = bid - 128;
    ws[WS_WR + a * 256 + tid] = W2g[tid * 128 + a];
  }
  if (tid < 256){                              // y0 = [z, 0]
    const int r = tid >> 3, jj = (tid & 7) * 4;
    const int base = (r0 + r) * 32 + jj;
    st4(&ws[WS_YZ + base], ld4(&z[base]));
  }
  if (tid < RB) ws[WS_YL + r0 + tid] = 0.f;

  const float trP = lds[L_MISC];
  const float t1 = 2.0f * Tg[0];

  grid.sync();

  // ================= main adaptive RK loop =================
  float t_cur = 0.f, dt_cur = 0.25f;
  bool prev_acc = false;

  for (int step = 0; step < 10; step++){
    if (t_cur >= t1 - 1e-9f) break;            // remaining reference steps no-op
    const float dtc = fminf(dt_cur, t1 - t_cur);

    // stages 1..6
    for (int s = 1; s <= 6; s++){
      if (s == 1 && step > 0){
        if (prev_acc){                         // FSAL: k1 = previous k7
          if (tid < 256){
            const int r = tid >> 3, jj = (tid & 7) * 4;
            const int base = (r0 + r) * 32 + jj;
            st4(&ws[WS_KZ + 0 * 262144 + base], ld4(&ws[WS_KZ + 6 * 262144 + base]));
          }
          if (tid < RB) ws[WS_KL + 0 * 8192 + r0 + tid] = ws[WS_KL + 6 * 8192 + r0 + tid];
        }                                       // rejected: k1 = f(y) unchanged
        continue;
      }
      assemble_x(lds, ws, r0, tid, dtc, ACO[s >= 2 ? s - 2 : 0], s - 1);
      eval_f(lds, ws, r0, tid, trP, s - 1);
    }

    // stage 7: y1, k7 = f(y1), error estimate
    __syncthreads();
    if (tid < 256){
      const int r = tid >> 3, jj = (tid & 7) * 4;
      const int base = (r0 + r) * 32 + jj;
      f4 y   = ld4(&ws[WS_YZ + base]);
      f4 k1v = ld4(&ws[WS_KZ + 0 * 262144 + base]);
      f4 k3v = ld4(&ws[WS_KZ + 2 * 262144 + base]);
      f4 k4v = ld4(&ws[WS_KZ + 3 * 262144 + base]);
      f4 k5v = ld4(&ws[WS_KZ + 4 * 262144 + base]);
      f4 k6v = ld4(&ws[WS_KZ + 5 * 262144 + base]);
      f4 x;
      x.x = y.x + dtc * (B1C*k1v.x + B3C*k3v.x + B4C*k4v.x + B5C*k5v.x + B6C*k6v.x);
      x.y = y.y + dtc * (B1C*k1v.y + B3C*k3v.y + B4C*k4v.y + B5C*k5v.y + B6C*k6v.y);
      x.z = y.z + dtc * (B1C*k1v.z + B3C*k3v.z + B4C*k4v.z + B5C*k5v.z + B6C*k6v.z);
      x.w = y.w + dtc * (B1C*k1v.w + B3C*k3v.w + B4C*k4v.w + B5C*k5v.w + B6C*k6v.w);
      st4(&ws[WS_Y1Z + base], x);
      lds[L_XST + (jj + 0) * 36 + r] = x.x;
      lds[L_XST + (jj + 1) * 36 + r] = x.y;
      lds[L_XST + (jj + 2) * 36 + r] = x.z;
      lds[L_XST + (jj + 3) * 36 + r] = x.w;
    }
    if (tid < RB){
      int n = r0 + tid;
      float s = B1C * ws[WS_KL + 0*8192 + n] + B3C * ws[WS_KL + 2*8192 + n]
              + B4C * ws[WS_KL + 3*8192 + n] + B5C * ws[WS_KL + 4*8192 + n]
              + B6C * ws[WS_KL + 5*8192 + n];
      ws[WS_Y1L + n] = ws[WS_YL + n] + dtc * s;
    }
    __syncthreads();
    eval_f(lds, ws, r0, tid, trP, 6);
    __syncthreads();

    float sacc = 0.f;
    if (tid < 256){
      const int r = tid >> 3, jj = (tid & 7) * 4;
      const int base = (r0 + r) * 32 + jj;
      f4 k1v = ld4(&ws[WS_KZ + 0 * 262144 + base]);
      f4 k3v = ld4(&ws[WS_KZ + 2 * 262144 + base]);
      f4 k4v = ld4(&ws[WS_KZ + 3 * 262144 + base]);
      f4 k5v = ld4(&ws[WS_KZ + 4 * 262144 + base]);
      f4 k6v = ld4(&ws[WS_KZ + 5 * 262144 + base]);
      f4 k7v = ld4(&ws[WS_KZ + 6 * 262144 + base]);
      f4 yv  = ld4(&ws[WS_YZ + base]);
      f4 y1v = ld4(&ws[WS_Y1Z + base]);
      float ev, tol, q;
      ev = dtc * (E1C*k1v.x + E3C*k3v.x + E4C*k4v.x + E5C*k5v.x + E6C*k6v.x + E7C*k7v.x);
      tol = 1e-5f + 1e-5f * fmaxf(fabsf(yv.x), fabsf(y1v.x)); q = ev / tol; sacc += q * q;
      ev = dtc * (E1C*k1v.y + E3C*k3v.y + E4C*k4v.y + E5C*k5v.y + E6C*k6v.y + E7C*k7v.y);
      tol = 1e-5f + 1e-5f * fmaxf(fabsf(yv.y), fabsf(y1v.y)); q = ev / tol; sacc += q * q;
      ev = dtc * (E1C*k1v.z + E3C*k3v.z + E4C*k4v.z + E5C*k5v.z + E6C*k6v.z + E7C*k7v.z);
      tol = 1e-5f + 1e-5f * fmaxf(fabsf(yv.z), fabsf(y1v.z)); q = ev / tol; sacc += q * q;
      ev = dtc * (E1C*k1v.w + E3C*k3v.w + E4C*k4v.w + E5C*k5v.w + E6C*k6v.w + E7C*k7v.w);
      tol = 1e-5f + 1e-5f * fmaxf(fabsf(yv.w), fabsf(y1v.w)); q = ev / tol; sacc += q * q;
    }
    if (tid < RB){
      int n = r0 + tid;
      float evl = dtc * (E1C * ws[WS_KL + 0*8192 + n] + E3C * ws[WS_KL + 2*8192 + n]
                + E4C * ws[WS_KL + 3*8192 + n] + E5C * ws[WS_KL + 4*8192 + n]
                + E6C * ws[WS_KL + 5*8192 + n] + E7C * ws[WS_KL + 6*8192 + n]);
      float toll = 1e-5f + 1e-5f * fmaxf(fabsf(ws[WS_YL + n]), fabsf(ws[WS_Y1L + n]));
      float ql = evl / toll; sacc += ql * ql;
    }
    lds[L_RED + tid] = sacc; __syncthreads();
    for (int o = 256; o > 0; o >>= 1){
      if (tid < o) lds[L_RED + tid] += lds[L_RED + tid + o];
      __syncthreads();
    }
    if (tid == 0) ws[WS_PART + step * 256 + bid] = lds[L_RED + 0];

    grid.sync();

    // deterministic global reduction (every block, identical order)
    if (tid < 256) lds[L_RED + tid] = ws[WS_PART + step * 256 + tid];
    __syncthreads();
    for (int o = 128; o > 0; o >>= 1){
      if (tid < o) lds[L_RED + tid] += lds[L_RED + tid + o];
      __syncthreads();
    }
    const float errn = sqrtf(lds[L_RED + 0] / 270336.0f);
    __syncthreads();

    const bool accept = (errn <= 1.0f);
    if (accept){
      if (tid < 256){
        const int r = tid >> 3, jj = (tid & 7) * 4;
        const int base = (r0 + r) * 32 + jj;
        st4(&ws[WS_YZ + base], ld4(&ws[WS_Y1Z + base]));
      }
      if (tid < RB) ws[WS_YL + r0 + tid] = ws[WS_Y1L + r0 + tid];
      t_cur += dtc;
    }
    float fac = 0.9f * powf(errn, -0.2f);
    fac = fminf(fmaxf(fac, 0.2f), 10.0f);
    dt_cur = fminf(fmaxf(dtc * fac, 1e-6f), t1);
    prev_acc = accept;
  }

  // ---- output: yT[:, :d] ----
  if (tid < 256){
    const int r = tid >> 3, jj = (tid & 7) * 4;
    const int base = (r0 + r) * 32 + jj;
    st4(&out[base], ld4(&ws[WS_YZ + base]));
  }
}

extern "C" void kernel_launch(void* const* d_in, const int* in_sizes, int n_in,
                              void* d_out, int out_size, void* d_ws, size_t ws_size,
                              hipStream_t stream)
{
  (void)in_sizes; (void)n_in; (void)out_size;
  const float* z  = (const float*)d_in[0];
  const float* Gw = (const float*)d_in[1];
  const float* W1 = (const float*)d_in[2];
  const float* b1 = (const float*)d_in[3];
  const float* W2 = (const float*)d_in[4];
  const float* b2 = (const float*)d_in[5];
  const float* W3 = (const float*)d_in[6];
  const float* b3 = (const float*)d_in[7];
  const float* T  = (const float*)d_in[8];
  float* out = (float*)d_out;
  float* ws  = (float*)d_ws;
  if (ws_size < (size_t)WS_TOTAL * sizeof(float)) return;

  void* args[] = { (void*)&z, (void*)&Gw, (void*)&W1, (void*)&b1, (void*)&W2,
                   (void*)&b2, (void*)&W3, (void*)&b3, (void*)&T, (void*)&out,
                   (void*)&ws };
  hipLaunchCooperativeKernel((const void*)qpnf_kernel, dim3(256), dim3(NT),
                             args, 0, stream);
}

// Round 9
// 1299.696 us; speedup vs baseline: 1.2651x; 1.0465x over previous
//
#include <hip/hip_runtime.h>
#include <hip/hip_cooperative_groups.h>
#include <math.h>

namespace cg = cooperative_groups;
typedef float4 f4;

#define NT 512          // 8 waves/block, 1 block/CU -> 2 waves/SIMD
#define RB 32           // rows per block; GRID=256 (cooperative cap)

// ---------------- workspace float offsets (weights + partials only) -------
#define WS_WR    0          // WR[128][256]: [k][0:128]=W2T row k, [k][128:256]=R row k
#define WS_PART  32768      // [10][256] err partials
#define WS_TOTAL 35328

// ---------------- LDS float offsets (129.8 KB) ----------------------------
#define L_W1T   0           // [32][128]  W1T[j][h] = W1[h][j]
#define L_C3T   4096        // [32][132]  C3T[c][b] = C3[b][c]
#define L_P     8320        // [32][32]   (init only)
#define L_PT    9344        // [32][36]   PT[c][q] = P[q][c]
#define L_HST   10496       // [128][36]  h1 transposed (init alias: IPW3)
#define L_HS2   15104       // [128][36]  h2 transposed
#define L_XST   19712       // [32][36]   x transposed (init alias: IP; loop alias: RED[512])
#define L_B1    20864
#define L_B2    20992
#define L_C0    21120
#define L_GS    21152       // [8][32]
#define L_AAUG  21408       // [8][16]
#define L_AINVG 21536       // [8][32]
#define L_MISC  21792       // [0]=trP
#define L_KZ    21796       // [7][32][36] k_z, pitch 36
#define L_KL    29860       // [7][32]     k_l
#define L_YZ    30084       // [32][36]    y_z
#define L_Y1Z   31236       // [32][36]    y1_z
#define L_YL    32388       // [32]
#define L_Y1L   32420       // [32]
#define LDS_FLOATS 32452
#define L_RED   L_XST       // [512] — XST is dead during the error reductions

__device__ const float ACO[5][5] = {
  { 0.2f, 0.f, 0.f, 0.f, 0.f },
  { (float)(3.0/40.0), (float)(9.0/40.0), 0.f, 0.f, 0.f },
  { (float)(44.0/45.0), (float)(-56.0/15.0), (float)(32.0/9.0), 0.f, 0.f },
  { (float)(19372.0/6561.0), (float)(-25360.0/2187.0), (float)(64448.0/6561.0), (float)(-212.0/729.0), 0.f },
  { (float)(9017.0/3168.0), (float)(-355.0/33.0), (float)(46732.0/5247.0), (float)(49.0/176.0), (float)(-5103.0/18656.0) }
};

#define B1C ((float)(35.0/384.0))
#define B3C ((float)(500.0/1113.0))
#define B4C ((float)(125.0/192.0))
#define B5C ((float)(-2187.0/6784.0))
#define B6C ((float)(11.0/84.0))

#define E1C ((float)(35.0/384.0 - 5179.0/57600.0))
#define E3C ((float)(500.0/1113.0 - 7571.0/16695.0))
#define E4C ((float)(125.0/192.0 - 393.0/640.0))
#define E5C ((float)(-2187.0/6784.0 + 92097.0/339200.0))
#define E6C ((float)(11.0/84.0 - 187.0/2100.0))
#define E7C ((float)(-1.0/40.0))

__device__ __forceinline__ f4 ld4(const float* p){ return *(const f4*)p; }
__device__ __forceinline__ void st4(float* p, f4 v){ *(f4*)p = v; }

// assemble x = y + dtc*sum_p co[p]*k[p] into xsT — all LDS
__device__ void assemble_x(float* lds, int tid, float dtc, const float* co, int np)
{
  __syncthreads();                 // prior phase-3 readers of XST done
  if (tid < 256){
    const int r = tid >> 3, jj = (tid & 7) * 4;
    const int o = r * 36 + jj;
    f4 y = ld4(&lds[L_YZ + o]);
    float sx = 0.f, sy = 0.f, sz = 0.f, sw = 0.f;
    for (int p = 0; p < np; p++){
      f4 kv = ld4(&lds[L_KZ + p * 1152 + o]);
      float c = co[p];
      sx += c * kv.x; sy += c * kv.y; sz += c * kv.z; sw += c * kv.w;
    }
    lds[L_XST + (jj + 0) * 36 + r] = y.x + dtc * sx;
    lds[L_XST + (jj + 1) * 36 + r] = y.y + dtc * sy;
    lds[L_XST + (jj + 2) * 36 + r] = y.z + dtc * sz;
    lds[L_XST + (jj + 3) * 36 + r] = y.w + dtc * sw;
  }
  __syncthreads();
}

// full f-eval: xsT -> L_KZ[kout], L_KL[kout]
// thread = (cg = tid&31: 4 cols, kh = (tid>>5)&1: k-half, wv = tid>>6: 4 rows)
__device__ void eval_f(float* lds, const float* __restrict__ ws, int tid,
                       float trP, int kout)
{
  const int cg = tid & 31, kh = (tid >> 5) & 1, wv = tid >> 6;
  const int row4 = 4 * wv;

  // ---- phase 1: h1 = relu(x @ W1^T + b1) -> HST ; k split over halves ----
  float a1[4][4];
#pragma unroll
  for (int i = 0; i < 4; i++)
#pragma unroll
    for (int j = 0; j < 4; j++) a1[i][j] = 0.f;
#pragma unroll 4
  for (int t = 0; t < 16; t++){
    const int k = kh * 16 + t;
    f4 av = ld4(&lds[L_XST + k * 36 + row4]);
    f4 bv = ld4(&lds[L_W1T + k * 128 + 4 * cg]);
    const float* ap = (const float*)&av;
    const float* bp = (const float*)&bv;
#pragma unroll
    for (int i = 0; i < 4; i++)
#pragma unroll
      for (int j = 0; j < 4; j++) a1[i][j] += bp[i] * ap[j];
  }
#pragma unroll
  for (int i = 0; i < 4; i++)
#pragma unroll
    for (int j = 0; j < 4; j++) a1[i][j] += __shfl_xor(a1[i][j], 32);
  if (kh == 0){
    f4 b1v = ld4(&lds[L_B1 + 4 * cg]);
    const float* b1p = (const float*)&b1v;
#pragma unroll
    for (int i = 0; i < 4; i++){
      f4 hv; float* hp = (float*)&hv;
#pragma unroll
      for (int j = 0; j < 4; j++) hp[j] = fmaxf(a1[i][j] + b1p[i], 0.f);
      st4(&lds[L_HST + (4 * cg + i) * 36 + row4], hv);
    }
  }
  __syncthreads();

  // ---- phase 2: ah = h1@W2^T, at = m1^T R ; WR interleaved L2 stream ----
  float ah[4][4], at[4][4];
#pragma unroll
  for (int i = 0; i < 4; i++)
#pragma unroll
    for (int j = 0; j < 4; j++){ ah[i][j] = 0.f; at[i][j] = 0.f; }
  const f4* WR4 = (const f4*)&ws[WS_WR];   // row k = 64 f4: [0:32)=W2T, [32:64)=R
  const int kb = kh * 64;
  f4 wb[4], rb[4];
#pragma unroll
  for (int u = 0; u < 4; u++){
    wb[u] = WR4[(kb + u) * 64 + cg];
    rb[u] = WR4[(kb + u) * 64 + 32 + cg];
  }
#pragma unroll 1
  for (int g = 0; g < 16; g++){
    f4 wc[4], rc[4];
#pragma unroll
    for (int u = 0; u < 4; u++){ wc[u] = wb[u]; rc[u] = rb[u]; }
    if (g < 15){
      const int kn = kb + (g + 1) * 4;
#pragma unroll
      for (int u = 0; u < 4; u++){
        wb[u] = WR4[(kn + u) * 64 + cg];
        rb[u] = WR4[(kn + u) * 64 + 32 + cg];
      }
    }
#pragma unroll
    for (int u = 0; u < 4; u++){
      const int k = kb + g * 4 + u;
      f4 av = ld4(&lds[L_HST + k * 36 + row4]);
      const float* ap = (const float*)&av;
      const float* wp = (const float*)&wc[u];
      const float* rp = (const float*)&rc[u];
      float m[4];
#pragma unroll
      for (int j = 0; j < 4; j++) m[j] = (ap[j] > 0.f) ? 1.f : 0.f;
#pragma unroll
      for (int i = 0; i < 4; i++)
#pragma unroll
        for (int j = 0; j < 4; j++){
          ah[i][j] += wp[i] * ap[j];
          at[i][j] += rp[i] * m[j];
        }
    }
  }
#pragma unroll
  for (int i = 0; i < 4; i++)
#pragma unroll
    for (int j = 0; j < 4; j++){
      ah[i][j] += __shfl_xor(ah[i][j], 32);
      at[i][j] += __shfl_xor(at[i][j], 32);
    }

  f4 b2v = ld4(&lds[L_B2 + 4 * cg]);
  const float* b2p = (const float*)&b2v;
  float h2v[4][4]; float dl[4] = {0.f, 0.f, 0.f, 0.f};
#pragma unroll
  for (int i = 0; i < 4; i++)
#pragma unroll
    for (int j = 0; j < 4; j++){
      float pre = ah[i][j] + b2p[i];
      float hv = fmaxf(pre, 0.f);
      h2v[i][j] = hv;
      if (pre > 0.f) dl[j] += at[i][j];
    }
#pragma unroll
  for (int mk = 1; mk < 32; mk <<= 1){
#pragma unroll
    for (int j = 0; j < 4; j++) dl[j] += __shfl_xor(dl[j], mk, 64);
  }
  // h2 -> HS2 (separate buffer, no barrier needed before store)
  if (kh == 0){
#pragma unroll
    for (int i = 0; i < 4; i++){
      f4 hv; float* hp = (float*)&hv;
#pragma unroll
      for (int j = 0; j < 4; j++) hp[j] = h2v[i][j];
      st4(&lds[L_HS2 + (4 * cg + i) * 36 + row4], hv);
    }
    if (cg == 0){
#pragma unroll
      for (int j = 0; j < 4; j++)
        lds[L_KL + kout * 32 + row4 + j] = dl[j] + trP;
    }
  }
  __syncthreads();                 // h2 visible

  // ---- phase 3: dz = -(h2 @ C3 + c0 + x @ P) -> L_KZ[kout] ----
  float a3[4] = {0.f, 0.f, 0.f, 0.f};
  const int bb = kh * 64;
#pragma unroll 4
  for (int t = 0; t < 16; t++){
    f4 cv = ld4(&lds[L_C3T + cg * 132 + bb + 4 * t]);
    const float* cp = (const float*)&cv;
#pragma unroll
    for (int u = 0; u < 4; u++){
      f4 av = ld4(&lds[L_HS2 + (bb + 4 * t + u) * 36 + row4]);
      const float* ap = (const float*)&av;
#pragma unroll
      for (int j = 0; j < 4; j++) a3[j] += ap[j] * cp[u];
    }
  }
  const int qq = kh * 16;
#pragma unroll
  for (int t = 0; t < 4; t++){
    f4 pv = ld4(&lds[L_PT + cg * 36 + qq + 4 * t]);
    const float* pp = (const float*)&pv;
#pragma unroll
    for (int u = 0; u < 4; u++){
      f4 av = ld4(&lds[L_XST + (qq + 4 * t + u) * 36 + row4]);
      const float* ap = (const float*)&av;
#pragma unroll
      for (int j = 0; j < 4; j++) a3[j] += ap[j] * pp[u];
    }
  }
#pragma unroll
  for (int j = 0; j < 4; j++) a3[j] += __shfl_xor(a3[j], 32);
  if (kh == 0){
    float c0v = lds[L_C0 + cg];
#pragma unroll
    for (int j = 0; j < 4; j++)
      lds[L_KZ + kout * 1152 + (row4 + j) * 36 + cg] = -(a3[j] + c0v);
  }
}

__global__ void __launch_bounds__(NT, 2)
qpnf_kernel(const float* __restrict__ z, const float* __restrict__ Gw,
            const float* __restrict__ W1g, const float* __restrict__ b1g,
            const float* __restrict__ W2g, const float* __restrict__ b2g,
            const float* __restrict__ W3g, const float* __restrict__ b3g,
            const float* __restrict__ Tg, float* __restrict__ out,
            float* __restrict__ ws)
{
  __shared__ float lds[LDS_FLOATS];
  const int tid = threadIdx.x;
  const int bid = blockIdx.x;
  const int r0 = bid * RB;
  cg::grid_group grid = cg::this_grid();

  // ================= init =================
  for (int i = 0; i < 8; i++){                // W1T[j][h] = W1[h][j]
    int idx = tid + i * NT;
    int h = idx >> 5, j = idx & 31;
    lds[L_W1T + j * 128 + h] = W1g[idx];
  }
  if (tid < 128){ lds[L_B1 + tid] = b1g[tid]; lds[L_B2 + tid] = b2g[tid]; }
  if (tid < 256) lds[L_GS + tid] = Gw[tid];
  __syncthreads();

  if (tid < 64){                              // A = G G^T (8x8), augmented
    int i = tid >> 3, j = tid & 7;
    float s = 0.f;
    for (int k = 0; k < 32; k++) s += lds[L_GS + i * 32 + k] * lds[L_GS + j * 32 + k];
    lds[L_AAUG + i * 16 + j] = s;
    lds[L_AAUG + i * 16 + 8 + j] = (i == j) ? 1.f : 0.f;
  }
  __syncthreads();
  if (tid == 0){                              // Gauss-Jordan, partial pivoting
    float* A = &lds[L_AAUG];
    for (int c = 0; c < 8; c++){
      int p = c; float mx = fabsf(A[c * 16 + c]);
      for (int r = c + 1; r < 8; r++){
        float v = fabsf(A[r * 16 + c]);
        if (v > mx){ mx = v; p = r; }
      }
      if (p != c)
        for (int q = 0; q < 16; q++){ float t = A[c*16+q]; A[c*16+q] = A[p*16+q]; A[p*16+q] = t; }
      float pv = 1.0f / A[c * 16 + c];
      for (int q = 0; q < 16; q++) A[c * 16 + q] *= pv;
      for (int r = 0; r < 8; r++) if (r != c){
        float fct = A[r * 16 + c];
        for (int q = 0; q < 16; q++) A[r * 16 + q] -= fct * A[c * 16 + q];
      }
    }
  }
  __syncthreads();
  if (tid < 256){                              // AinvG[m][d]
    int m = tid >> 5, d = tid & 31;
    float s = 0.f;
    for (int q = 0; q < 8; q++) s += lds[L_AAUG + m * 16 + 8 + q] * lds[L_GS + q * 32 + d];
    lds[L_AINVG + m * 32 + d] = s;
  }
  __syncthreads();
  for (int i4 = 0; i4 < 2; i4++){              // P = G^T AinvG
    int idx = tid + i4 * NT;
    int i = idx >> 5, j = idx & 31;
    float s = 0.f;
    for (int m = 0; m < 8; m++) s += lds[L_GS + m * 32 + i] * lds[L_AINVG + m * 32 + j];
    lds[L_P + i * 32 + j] = s;
  }
  __syncthreads();
  float* IPl = &lds[L_XST];                    // IP aliases XST during init
  for (int i4 = 0; i4 < 2; i4++){
    int idx = tid + i4 * NT;
    int i = idx >> 5, j = idx & 31;
    IPl[i * 32 + j] = ((i == j) ? 1.f : 0.f) - lds[L_P + i * 32 + j];
  }
  if (tid == 0){
    float s = 0.f;
    for (int i = 0; i < 32; i++) s += lds[L_P + i * 32 + i];
    lds[L_MISC] = s;                           // trP
  }
  __syncthreads();
  for (int i4 = 0; i4 < 8; i4++){              // C3T[c][b] = sum_i W3[i][b] IP[i][c]
    int idx = tid + i4 * NT;
    int b = idx & 127, c = idx >> 7;
    float s = 0.f;
    for (int i = 0; i < 32; i++) s += W3g[i * 128 + b] * IPl[i * 32 + c];
    lds[L_C3T + c * 132 + b] = s;
  }
  for (int i4 = 0; i4 < 2; i4++){              // PT[c][q] = P[q][c]
    int idx = tid + i4 * NT;
    int c = idx >> 5, q = idx & 31;
    lds[L_PT + c * 36 + q] = lds[L_P + q * 32 + c];
  }
  if (tid < 32){                               // c0 = b3 @ IP
    float s = 0.f;
    for (int i = 0; i < 32; i++) s += b3g[i] * IPl[i * 32 + tid];
    lds[L_C0 + tid] = s;
  }
  for (int i4 = 0; i4 < 8; i4++){              // IPW3[j][b] (aliases HST)
    int idx = tid + i4 * NT;
    int j = idx >> 7, b = idx & 127;
    float s = 0.f;
    for (int k = 0; k < 32; k++) s += IPl[j * 32 + k] * W3g[k * 128 + b];
    lds[L_HST + j * 128 + b] = s;
  }
  __syncthreads();
  if (bid < 128 && tid < 128){                 // R row a=bid -> WR[a][128+b]
    int a = bid;
    float s = 0.f;
    for (int j = 0; j < 32; j++) s += W1g[a * 32 + j] * lds[L_HST + j * 128 + tid];
    ws[WS_WR + a * 256 + 128 + tid] = s * W2g[tid * 128 + a];
  }
  if (bid >= 128 && tid < 128){                // W2T row a -> WR[a][b]
    int a = bid - 128;
    ws[WS_WR + a * 256 + tid] = W2g[tid * 128 + a];
  }
  if (tid < 256){                              // y0 = [z, 0] -> LDS
    const int r = tid >> 3, jj = (tid & 7) * 4;
    st4(&lds[L_YZ + r * 36 + jj], ld4(&z[(r0 + r) * 32 + jj]));
  }
  if (tid < RB) lds[L_YL + tid] = 0.f;

  const float trP = lds[L_MISC];
  const float t1 = 2.0f * Tg[0];

  grid.sync();

  // ================= main adaptive RK loop =================
  float t_cur = 0.f, dt_cur = 0.25f;
  bool prev_acc = false;

  for (int step = 0; step < 10; step++){
    if (t_cur >= t1 - 1e-9f) break;            // remaining reference steps no-op
    const float dtc = fminf(dt_cur, t1 - t_cur);

    // stages 1..6
    for (int s = 1; s <= 6; s++){
      if (s == 1 && step > 0){
        if (prev_acc){                         // FSAL: k1 = previous k7 (LDS copy)
          if (tid < 256){
            const int r = tid >> 3, jj = (tid & 7) * 4;
            const int o = r * 36 + jj;
            st4(&lds[L_KZ + o], ld4(&lds[L_KZ + 6 * 1152 + o]));
          }
          if (tid < RB) lds[L_KL + tid] = lds[L_KL + 6 * 32 + tid];
        }                                       // rejected: k1 = f(y) unchanged
        continue;
      }
      assemble_x(lds, tid, dtc, ACO[s >= 2 ? s - 2 : 0], s - 1);
      eval_f(lds, ws, tid, trP, s - 1);
    }

    // stage 7: y1, k7 = f(y1), error estimate
    __syncthreads();
    if (tid < 256){
      const int r = tid >> 3, jj = (tid & 7) * 4;
      const int o = r * 36 + jj;
      f4 y   = ld4(&lds[L_YZ + o]);
      f4 k1v = ld4(&lds[L_KZ + 0 * 1152 + o]);
      f4 k3v = ld4(&lds[L_KZ + 2 * 1152 + o]);
      f4 k4v = ld4(&lds[L_KZ + 3 * 1152 + o]);
      f4 k5v = ld4(&lds[L_KZ + 4 * 1152 + o]);
      f4 k6v = ld4(&lds[L_KZ + 5 * 1152 + o]);
      f4 x;
      x.x = y.x + dtc * (B1C*k1v.x + B3C*k3v.x + B4C*k4v.x + B5C*k5v.x + B6C*k6v.x);
      x.y = y.y + dtc * (B1C*k1v.y + B3C*k3v.y + B4C*k4v.y + B5C*k5v.y + B6C*k6v.y);
      x.z = y.z + dtc * (B1C*k1v.z + B3C*k3v.z + B4C*k4v.z + B5C*k5v.z + B6C*k6v.z);
      x.w = y.w + dtc * (B1C*k1v.w + B3C*k3v.w + B4C*k4v.w + B5C*k5v.w + B6C*k6v.w);
      st4(&lds[L_Y1Z + o], x);
      lds[L_XST + (jj + 0) * 36 + r] = x.x;
      lds[L_XST + (jj + 1) * 36 + r] = x.y;
      lds[L_XST + (jj + 2) * 36 + r] = x.z;
      lds[L_XST + (jj + 3) * 36 + r] = x.w;
    }
    if (tid < RB){
      float s = B1C * lds[L_KL + 0*32 + tid] + B3C * lds[L_KL + 2*32 + tid]
              + B4C * lds[L_KL + 3*32 + tid] + B5C * lds[L_KL + 4*32 + tid]
              + B6C * lds[L_KL + 5*32 + tid];
      lds[L_Y1L + tid] = lds[L_YL + tid] + dtc * s;
    }
    __syncthreads();
    eval_f(lds, ws, tid, trP, 6);
    __syncthreads();

    float sacc = 0.f;
    if (tid < 256){
      const int r = tid >> 3, jj = (tid & 7) * 4;
      const int o = r * 36 + jj;
      f4 k1v = ld4(&lds[L_KZ + 0 * 1152 + o]);
      f4 k3v = ld4(&lds[L_KZ + 2 * 1152 + o]);
      f4 k4v = ld4(&lds[L_KZ + 3 * 1152 + o]);
      f4 k5v = ld4(&lds[L_KZ + 4 * 1152 + o]);
      f4 k6v = ld4(&lds[L_KZ + 5 * 1152 + o]);
      f4 k7v = ld4(&lds[L_KZ + 6 * 1152 + o]);
      f4 yv  = ld4(&lds[L_YZ + o]);
      f4 y1v = ld4(&lds[L_Y1Z + o]);
      float ev, tol, q;
      ev = dtc * (E1C*k1v.x + E3C*k3v.x + E4C*k4v.x + E5C*k5v.x + E6C*k6v.x + E7C*k7v.x);
      tol = 1e-5f + 1e-5f * fmaxf(fabsf(yv.x), fabsf(y1v.x)); q = ev / tol; sacc += q * q;
      ev = dtc * (E1C*k1v.y + E3C*k3v.y + E4C*k4v.y + E5C*k5v.y + E6C*k6v.y + E7C*k7v.y);
      tol = 1e-5f + 1e-5f * fmaxf(fabsf(yv.y), fabsf(y1v.y)); q = ev / tol; sacc += q * q;
      ev = dtc * (E1C*k1v.z + E3C*k3v.z + E4C*k4v.z + E5C*k5v.z + E6C*k6v.z + E7C*k7v.z);
      tol = 1e-5f + 1e-5f * fmaxf(fabsf(yv.z), fabsf(y1v.z)); q = ev / tol; sacc += q * q;
      ev = dtc * (E1C*k1v.w + E3C*k3v.w + E4C*k4v.w + E5C*k5v.w + E6C*k6v.w + E7C*k7v.w);
      tol = 1e-5f + 1e-5f * fmaxf(fabsf(yv.w), fabsf(y1v.w)); q = ev / tol; sacc += q * q;
    }
    if (tid < RB){
      float evl = dtc * (E1C * lds[L_KL + 0*32 + tid] + E3C * lds[L_KL + 2*32 + tid]
                + E4C * lds[L_KL + 3*32 + tid] + E5C * lds[L_KL + 4*32 + tid]
                + E6C * lds[L_KL + 5*32 + tid] + E7C * lds[L_KL + 6*32 + tid]);
      float toll = 1e-5f + 1e-5f * fmaxf(fabsf(lds[L_YL + tid]), fabsf(lds[L_Y1L + tid]));
      float ql = evl / toll; sacc += ql * ql;
    }
    __syncthreads();               // KZ/KL/Y reads done before RED aliases XST-adjacent use
    lds[L_RED + tid] = sacc; __syncthreads();
    for (int o = 256; o > 0; o >>= 1){
      if (tid < o) lds[L_RED + tid] += lds[L_RED + tid + o];
      __syncthreads();
    }
    if (tid == 0) ws[WS_PART + step * 256 + bid] = lds[L_RED + 0];

    grid.sync();

    // deterministic global reduction (every block, identical order)
    if (tid < 256) lds[L_RED + tid] = ws[WS_PART + step * 256 + tid];
    __syncthreads();
    for (int o = 128; o > 0; o >>= 1){
      if (tid < o) lds[L_RED + tid] += lds[L_RED + tid + o];
      __syncthreads();
    }
    const float errn = sqrtf(lds[L_RED + 0] / 270336.0f);
    __syncthreads();

    const bool accept = (errn <= 1.0f);
    if (accept){
      if (tid < 256){
        const int r = tid >> 3, jj = (tid & 7) * 4;
        const int o = r * 36 + jj;
        st4(&lds[L_YZ + o], ld4(&lds[L_Y1Z + o]));
      }
      if (tid < RB) lds[L_YL + tid] = lds[L_Y1L + tid];
      t_cur += dtc;
    }
    float fac = 0.9f * powf(errn, -0.2f);
    fac = fminf(fmaxf(fac, 0.2f), 10.0f);
    dt_cur = fminf(fmaxf(dtc * fac, 1e-6f), t1);
    prev_acc = accept;
  }

  // ---- output: yT[:, :d] ----
  __syncthreads();
  if (tid < 256){
    const int r = tid >> 3, jj = (tid & 7) * 4;
    st4(&out[(r0 + r) * 32 + jj], ld4(&lds[L_YZ + r * 36 + jj]));
  }
}

extern "C" void kernel_launch(void* const* d_in, const int* in_sizes, int n_in,
                              void* d_out, int out_size, void* d_ws, size_t ws_size,
                              hipStream_t stream)
{
  (void)in_sizes; (void)n_in; (void)out_size;
  const float* z  = (const float*)d_in[0];
  const float* Gw = (const float*)d_in[1];
  const float* W1 = (const float*)d_in[2];
  const float* b1 = (const float*)d_in[3];
  const float* W2 = (const float*)d_in[4];
  const float* b2 = (const float*)d_in[5];
  const float* W3 = (const float*)d_in[6];
  const float* b3 = (const float*)d_in[7];
  const float* T  = (const float*)d_in[8];
  float* out = (float*)d_out;
  float* ws  = (float*)d_ws;
  if (ws_size < (size_t)WS_TOTAL * sizeof(float)) return;

  void* args[] = { (void*)&z, (void*)&Gw, (void*)&W1, (void*)&b1, (void*)&W2,
                   (void*)&b2, (void*)&W3, (void*)&b3, (void*)&T, (void*)&out,
                   (void*)&ws };
  hipLaunchCooperativeKernel((const void*)qpnf_kernel, dim3(256), dim3(NT),
                             args, 0, stream);
}